// Round 11
// baseline (183.480 us; speedup 1.0000x reference)
//
#include <hip/hip_runtime.h>
#include <math.h>

#define F 256
#define TBL 2048
#define SMAX 8.0f
#define EPS 1e-8f
#define NBLK 1024               // k_run grid: 4096 waves
#define MAXCH 6                 // up to 384 rows/batch in registers
#define TROWS 8                 // table rows per prep block
#define TBLB (TBL / TROWS)      // 256 table blocks
#define PREP_U 256              // u blocks
#define PREP_C (PREP_U)         // c0 block id
#define PREP_S (PREP_U + 1)     // first bstart block
#define NSB 17                  // bstart blocks (covers B+1 = 4097)
#define PREP_T (PREP_S + NSB)   // first table block

typedef float f4 __attribute__((ext_vector_type(4)));

__device__ __forceinline__ float softplus_f(float t) {
    float p = exp2f(-fabsf(t) * 1.44269504089f);
    return fmaxf(t, 0.f) + 0.69314718056f * log2f(1.f + p);
}

__device__ __forceinline__ int lower_bound_i(const int* __restrict__ a, int n, int v) {
    int lo = 0, hi = n;
    while (lo < hi) {
        int mid = (lo + hi) >> 1;
        if (a[mid] < v) lo = mid + 1; else hi = mid;
    }
    return lo;
}

// ---------------------------------------------------------------------------
// k_prep: blocks [0,256): u[g]   | block 256: c0 | blocks [257,274): bstart
//         blocks [274, 274+256): table, 8 rows each
// ---------------------------------------------------------------------------
__global__ __launch_bounds__(256)
void k_prep(const float* __restrict__ Wq, const float* __restrict__ bq,
            const float* __restrict__ Wk, const int* __restrict__ seg,
            const float* __restrict__ Wv, const float* __restrict__ W1,
            const float* __restrict__ b1v, const float* __restrict__ W2,
            const float* __restrict__ b2v, float* __restrict__ u,
            float* __restrict__ c0, int* __restrict__ bstart,
            float* __restrict__ table, int B, int N)
{
    const int t = threadIdx.x;
    const int g = blockIdx.x;

    if (g < PREP_U || g == PREP_C) {
        __shared__ float red[256];
        float p;
        if (g < PREP_U) p = Wk[t] * Wq[(size_t)t * F + g];
        else            p = Wk[t] * bq[t];
        red[t] = p;
        __syncthreads();
        #pragma unroll
        for (int s = 128; s > 0; s >>= 1) {
            if (t < s) red[t] += red[t + s];
            __syncthreads();
        }
        if (t == 0) { if (g < PREP_U) u[g] = red[0]; else *c0 = red[0]; }
        return;
    }

    if (g < PREP_T) {
        int j = (g - PREP_S) * 256 + t;
        if (j <= B) bstart[j] = lower_bound_i(seg, N, j);
        return;
    }

    // ----- table build: 8 rows per block -----
    __shared__ float zbuf[TROWS][F];
    const int tb = g - PREP_T;
    const int i  = t;
    const float delta = SMAX / (float)(TBL - 1);
    const float wv = Wv[i];

    #pragma unroll
    for (int r = 0; r < TROWS; ++r) {
        float s  = (float)(tb * TROWS + r) * delta;
        float zv = s * wv;
        zbuf[r][i] = zv / (1.f + __expf(-zv));               // silu(y)
    }
    __syncthreads();

    float acc[TROWS];
    float bb = b1v[i];
    #pragma unroll
    for (int r = 0; r < TROWS; ++r) acc[r] = bb;
    const f4* w1row = (const f4*)(W1 + (size_t)i * F);
    for (int fc = 0; fc < F / 4; ++fc) {
        f4 w4 = w1row[fc];
        #pragma unroll
        for (int r = 0; r < TROWS; ++r) {
            f4 z4 = *(const f4*)&zbuf[r][fc * 4];
            acc[r] += w4.x * z4.x + w4.y * z4.y + w4.z * z4.z + w4.w * z4.w;
        }
    }
    __syncthreads();
    #pragma unroll
    for (int r = 0; r < TROWS; ++r)
        zbuf[r][i] = acc[r] / (1.f + __expf(-acc[r]));       // silu(h1)
    __syncthreads();

    bb = b2v[i];
    #pragma unroll
    for (int r = 0; r < TROWS; ++r) acc[r] = bb;
    const f4* w2row = (const f4*)(W2 + (size_t)i * F);
    for (int fc = 0; fc < F / 4; ++fc) {
        f4 w4 = w2row[fc];
        #pragma unroll
        for (int r = 0; r < TROWS; ++r) {
            f4 z4 = *(const f4*)&zbuf[r][fc * 4];
            acc[r] += w4.x * z4.x + w4.y * z4.y + w4.z * z4.z + w4.w * z4.w;
        }
    }
    #pragma unroll
    for (int r = 0; r < TROWS; ++r) {
        float s = (float)(tb * TROWS + r) * delta;
        table[(size_t)(tb * TROWS + r) * F + i] = s * wv + acc[r];
    }
}

// ---------------------------------------------------------------------------
// phase-A round: 4 rows per round, 16-lane-per-row layout (proven in R9)
// ---------------------------------------------------------------------------
template <bool GUARD>
__device__ __forceinline__ void roundA(const float* __restrict__ x, int m0,
                                       int rlim, int j, int rsub, int kc,
                                       const f4* uf, int lane, float& dval)
{
    int row = m0 + (j << 2) + rsub;
    f4 v0 = {0.f, 0.f, 0.f, 0.f}, v1 = v0, v2 = v0, v3 = v0;
    if (!GUARD || row < rlim) {
        const float* xr = x + (size_t)row * F + (kc << 2);
        v0 = __builtin_nontemporal_load((const f4*)xr);
        v1 = __builtin_nontemporal_load((const f4*)(xr + 64));
        v2 = __builtin_nontemporal_load((const f4*)(xr + 128));
        v3 = __builtin_nontemporal_load((const f4*)(xr + 192));
    }
    float dA = v0.x * uf[0].x + v0.y * uf[0].y + v0.z * uf[0].z + v0.w * uf[0].w;
    float dB = v1.x * uf[1].x + v1.y * uf[1].y + v1.z * uf[1].z + v1.w * uf[1].w;
    float dC = v2.x * uf[2].x + v2.y * uf[2].y + v2.z * uf[2].z + v2.w * uf[2].w;
    float dD = v3.x * uf[3].x + v3.y * uf[3].y + v3.z * uf[3].z + v3.w * uf[3].w;
    float d = (dA + dB) + (dC + dD);
    d += __shfl_xor(d, 1);
    d += __shfl_xor(d, 2);
    d += __shfl_xor(d, 4);
    d += __shfl_xor(d, 8);
    float got = __shfl(d, (lane & 3) << 4);
    if ((lane >> 2) == j) dval = got;
}

// one 64-row chunk: returns this lane's a (0 if invalid), adds chunk sum to asum
__device__ __forceinline__ float chunkA(const float* __restrict__ x, int m0,
                                        int rlim, int rsub, int kc,
                                        const f4* uf, int lane, float c0v,
                                        float e, float& asum)
{
    const int cr = min(64, rlim - m0);
    float dval = 0.f;
    if (cr == 64) {
        #pragma unroll 4
        for (int j = 0; j < 16; ++j)
            roundA<false>(x, m0, rlim, j, rsub, kc, uf, lane, dval);
    } else {
        for (int j = 0; j < 16; ++j)
            roundA<true>(x, m0, rlim, j, rsub, kc, uf, lane, dval);
    }
    float a = 0.f;
    if (lane < cr) a = softplus_f(e * (dval + c0v) * 0.0625f);
    float s = a;
    #pragma unroll
    for (int off = 1; off < 64; off <<= 1) s += __shfl_xor(s, off);
    asum += s;
    return a;
}

// one 64-row output chunk: idx from a, gather table row, NT store
__device__ __forceinline__ void chunkOut(const float* __restrict__ table,
                                         float* __restrict__ out, int m0,
                                         int rlim, int lane, float a,
                                         float sscale, float invd)
{
    const int cr = min(64, rlim - m0);
    int idx = 0;
    if (lane < cr) {
        int i0 = (int)(a * sscale * invd + 0.5f);
        idx = min(max(i0, 0), TBL - 1) * F;
    }
    if (cr == 64) {
        #pragma unroll
        for (int r = 0; r < 64; r += 4) {
            int i0 = __builtin_amdgcn_readlane(idx, r);
            int i1 = __builtin_amdgcn_readlane(idx, r + 1);
            int i2 = __builtin_amdgcn_readlane(idx, r + 2);
            int i3 = __builtin_amdgcn_readlane(idx, r + 3);
            f4 t0 = *((const f4*)(table + i0) + lane);
            f4 t1 = *((const f4*)(table + i1) + lane);
            f4 t2 = *((const f4*)(table + i2) + lane);
            f4 t3 = *((const f4*)(table + i3) + lane);
            __builtin_nontemporal_store(t0, (f4*)(out + (size_t)(m0 + r)     * F) + lane);
            __builtin_nontemporal_store(t1, (f4*)(out + (size_t)(m0 + r + 1) * F) + lane);
            __builtin_nontemporal_store(t2, (f4*)(out + (size_t)(m0 + r + 2) * F) + lane);
            __builtin_nontemporal_store(t3, (f4*)(out + (size_t)(m0 + r + 3) * F) + lane);
        }
    } else {
        for (int r = 0; r < cr; ++r) {
            int i0 = __shfl(idx, r);
            f4 t0 = *((const f4*)(table + i0) + lane);
            __builtin_nontemporal_store(t0, (f4*)(out + (size_t)(m0 + r) * F) + lane);
        }
    }
}

// ---------------------------------------------------------------------------
// k_run: wave w owns all batches whose start row lies in [w*win, (w+1)*win).
// Per batch: phase 1 (a in regs, exact anorm via wave reduce), phase 2
// (gather+store). No atomics, no inter-wave communication.
// ---------------------------------------------------------------------------
__global__ __launch_bounds__(256)
void k_run(const float* __restrict__ x, const float* __restrict__ E,
           const float* __restrict__ u, const float* __restrict__ c0p,
           const int* __restrict__ bstart, const float* __restrict__ table,
           float* __restrict__ out, int N, int B)
{
    const int lane = threadIdx.x & 63;
    const int wid  = threadIdx.x >> 6;
    const int w    = blockIdx.x * 4 + wid;
    const int NW   = NBLK * 4;
    const int win  = (N + NW - 1) / NW;
    const int lo   = w * win;
    if (lo >= N) return;
    const int hi = min(lo + win, N);

    const int rsub = lane >> 4;
    const int kc   = lane & 15;
    f4 uf[4];
    #pragma unroll
    for (int kk = 0; kk < 4; ++kk)
        uf[kk] = *(const f4*)(u + (kc << 2) + (kk << 6));
    const float c0v = *c0p;
    const float invd = (float)(TBL - 1) / SMAX;

    // first batch with bstart[b] >= lo (search over [0, B+1))
    int b;
    {
        int l = 0, h = B + 1;
        while (l < h) { int m = (l + h) >> 1; if (bstart[m] < lo) l = m + 1; else h = m; }
        b = l;
    }

    for (; b < B && bstart[b] < hi; ++b) {
        const int r0 = bstart[b], r1 = bstart[b + 1];
        const int R = r1 - r0;
        if (R == 0) continue;
        const float e = fabsf(E[b]);
        const int nch = (R + 63) >> 6;

        float areg[MAXCH];
        float asum = 0.f;
        #pragma unroll
        for (int j = 0; j < MAXCH; ++j) {
            if (j >= nch) break;
            areg[j] = chunkA(x, r0 + (j << 6), r1, rsub, kc, uf, lane, c0v, e, asum);
        }
        for (int j = MAXCH; j < nch; ++j)
            (void)chunkA(x, r0 + (j << 6), r1, rsub, kc, uf, lane, c0v, e, asum);

        const float sscale = e / (asum + EPS);
        #pragma unroll
        for (int j = 0; j < MAXCH; ++j) {
            if (j >= nch) break;
            chunkOut(table, out, r0 + (j << 6), r1, lane, areg[j], sscale, invd);
        }
        for (int j = MAXCH; j < nch; ++j) {            // rare tail: recompute a
            float dummy = 0.f;
            float a = chunkA(x, r0 + (j << 6), r1, rsub, kc, uf, lane, c0v, e, dummy);
            chunkOut(table, out, r0 + (j << 6), r1, lane, a, sscale, invd);
        }
    }
}

// ---------------------------------------------------------------------------
extern "C" void kernel_launch(void* const* d_in, const int* in_sizes, int n_in,
                              void* d_out, int out_size, void* d_ws, size_t ws_size,
                              hipStream_t stream)
{
    const float* x   = (const float*)d_in[0];
    const float* E   = (const float*)d_in[1];
    const int*   seg = (const int*)  d_in[2];
    const float* Wq  = (const float*)d_in[4];
    const float* bq  = (const float*)d_in[5];
    const float* Wk  = (const float*)d_in[6];
    const float* Wv  = (const float*)d_in[7];
    const float* W1  = (const float*)d_in[8];
    const float* b1  = (const float*)d_in[9];
    const float* W2  = (const float*)d_in[10];
    const float* b2  = (const float*)d_in[11];

    const int N = in_sizes[0] / F;
    const int B = in_sizes[1];
    float* out = (float*)d_out;

    float* ws     = (float*)d_ws;
    float* table  = ws;                          // TBL*F floats (2 MB)
    float* u      = table + (size_t)TBL * F;     // F
    float* c0     = u + F;                       // 1 (padded to 4)
    int*   bstart = (int*)(c0 + 4);              // B+1

    k_prep<<<PREP_T + TBLB, 256, 0, stream>>>(Wq, bq, Wk, seg, Wv, W1, b1, W2,
                                              b2, u, c0, bstart, table, B, N);

    k_run<<<NBLK, 256, 0, stream>>>(x, E, u, c0, bstart, table, out, N, B);
}

// Round 12
// 147.867 us; speedup vs baseline: 1.2408x; 1.2408x over previous
//
#include <hip/hip_runtime.h>
#include <math.h>

#define F 256
#define TBL 2048
#define TBLK (TBL / 16)      // 128 table-builder blocks
#define GA 1920              // phase-A blocks: 7680 waves, 40 rows/wave
#define SMAX 8.0f
#define EPS 1e-8f

typedef float f4 __attribute__((ext_vector_type(4)));

__device__ __forceinline__ float softplus_f(float t) {
    float p = exp2f(-fabsf(t) * 1.44269504089f);
    return fmaxf(t, 0.f) + 0.69314718056f * log2f(1.f + p);
}

// ---------------------------------------------------------------------------
// k_prep (wide): block g<F computes u[g]; block F: c0. anorm zeroed.
// ---------------------------------------------------------------------------
__global__ __launch_bounds__(256)
void k_prep(const float* __restrict__ Wq, const float* __restrict__ bq,
            const float* __restrict__ Wk, float* __restrict__ u,
            float* __restrict__ c0, float* __restrict__ anorm, int B)
{
    __shared__ float red[256];
    const int t = threadIdx.x;
    const int g = blockIdx.x;

    int j = g * 256 + t;
    if (j < B) anorm[j] = 0.f;

    float p;
    if (g < F) p = Wk[t] * Wq[(size_t)t * F + g];
    else       p = Wk[t] * bq[t];
    red[t] = p;
    __syncthreads();
    #pragma unroll
    for (int s = 128; s > 0; s >>= 1) {
        if (t < s) red[t] += red[t + s];
        __syncthreads();
    }
    if (t == 0) {
        if (g < F) u[g] = red[0];
        else       *c0 = red[0];
    }
}

// ---------------------------------------------------------------------------
// k_main: blocks [0,TBLK): table g(s)=s*Wv+h2(s); blocks [TBLK,..): phase A
// with 8 rows in flight per iteration.
// ---------------------------------------------------------------------------
__global__ __launch_bounds__(256)
void k_main(const float* __restrict__ x, const float* __restrict__ E,
            const int* __restrict__ seg, const float* __restrict__ u,
            const float* __restrict__ c0p, const float* __restrict__ Wv,
            const float* __restrict__ W1, const float* __restrict__ b1,
            const float* __restrict__ W2, const float* __restrict__ b2,
            float* __restrict__ a_arr, float* __restrict__ anorm,
            float* __restrict__ table, int N)
{
    __shared__ float zbuf[16][F];

    if ((int)blockIdx.x >= TBLK) {
        const int lane = threadIdx.x & 63;
        const int wid  = threadIdx.x >> 6;
        const int gwave = (blockIdx.x - TBLK) * 4 + wid;
        const int total_waves = GA * 4;
        const int chunk = (N + total_waves - 1) / total_waves;
        const int n0 = gwave * chunk;
        const int n1 = min(n0 + chunk, N);
        if (n0 >= n1) return;

        const f4 u4 = ((const f4*)u)[lane];
        const float c0 = *c0p;

        int   curb = seg[n0];
        float accA = 0.f;

        int n = n0;
        for (; n + 7 < n1; n += 8) {
            const f4* xp = (const f4*)(x + (size_t)n * F) + lane;
            f4 r0 = __builtin_nontemporal_load(xp);
            f4 r1 = __builtin_nontemporal_load(xp + 64);
            f4 r2 = __builtin_nontemporal_load(xp + 128);
            f4 r3 = __builtin_nontemporal_load(xp + 192);
            f4 r4 = __builtin_nontemporal_load(xp + 256);
            f4 r5 = __builtin_nontemporal_load(xp + 320);
            f4 r6 = __builtin_nontemporal_load(xp + 384);
            f4 r7 = __builtin_nontemporal_load(xp + 448);
            float d0 = r0.x * u4.x + r0.y * u4.y + r0.z * u4.z + r0.w * u4.w;
            float d1 = r1.x * u4.x + r1.y * u4.y + r1.z * u4.z + r1.w * u4.w;
            float d2 = r2.x * u4.x + r2.y * u4.y + r2.z * u4.z + r2.w * u4.w;
            float d3 = r3.x * u4.x + r3.y * u4.y + r3.z * u4.z + r3.w * u4.w;
            float d4 = r4.x * u4.x + r4.y * u4.y + r4.z * u4.z + r4.w * u4.w;
            float d5 = r5.x * u4.x + r5.y * u4.y + r5.z * u4.z + r5.w * u4.w;
            float d6 = r6.x * u4.x + r6.y * u4.y + r6.z * u4.z + r6.w * u4.w;
            float d7 = r7.x * u4.x + r7.y * u4.y + r7.z * u4.z + r7.w * u4.w;
            #pragma unroll
            for (int off = 32; off; off >>= 1) {
                d0 += __shfl_xor(d0, off);
                d1 += __shfl_xor(d1, off);
                d2 += __shfl_xor(d2, off);
                d3 += __shfl_xor(d3, off);
                d4 += __shfl_xor(d4, off);
                d5 += __shfl_xor(d5, off);
                d6 += __shfl_xor(d6, off);
                d7 += __shfl_xor(d7, off);
            }
            int b0 = seg[n],     b1i = seg[n + 1], b2i = seg[n + 2], b3 = seg[n + 3];
            int b4 = seg[n + 4], b5  = seg[n + 5], b6  = seg[n + 6], b7 = seg[n + 7];
            float a0 = softplus_f(fabsf(E[b0])  * (d0 + c0) * 0.0625f);
            float a1 = softplus_f(fabsf(E[b1i]) * (d1 + c0) * 0.0625f);
            float a2 = softplus_f(fabsf(E[b2i]) * (d2 + c0) * 0.0625f);
            float a3 = softplus_f(fabsf(E[b3])  * (d3 + c0) * 0.0625f);
            float a4 = softplus_f(fabsf(E[b4])  * (d4 + c0) * 0.0625f);
            float a5 = softplus_f(fabsf(E[b5])  * (d5 + c0) * 0.0625f);
            float a6 = softplus_f(fabsf(E[b6])  * (d6 + c0) * 0.0625f);
            float a7 = softplus_f(fabsf(E[b7])  * (d7 + c0) * 0.0625f);
            float av = a0;
            av = (lane == 1) ? a1 : av;
            av = (lane == 2) ? a2 : av;
            av = (lane == 3) ? a3 : av;
            av = (lane == 4) ? a4 : av;
            av = (lane == 5) ? a5 : av;
            av = (lane == 6) ? a6 : av;
            av = (lane == 7) ? a7 : av;
            if (lane < 8) a_arr[n + lane] = av;
            if (lane == 0) {
                if (b0 != curb) { atomicAdd(&anorm[curb], accA); accA = 0.f; curb = b0; }
                accA += a0;
                if (b1i != curb) { atomicAdd(&anorm[curb], accA); accA = 0.f; curb = b1i; }
                accA += a1;
                if (b2i != curb) { atomicAdd(&anorm[curb], accA); accA = 0.f; curb = b2i; }
                accA += a2;
                if (b3 != curb) { atomicAdd(&anorm[curb], accA); accA = 0.f; curb = b3; }
                accA += a3;
                if (b4 != curb) { atomicAdd(&anorm[curb], accA); accA = 0.f; curb = b4; }
                accA += a4;
                if (b5 != curb) { atomicAdd(&anorm[curb], accA); accA = 0.f; curb = b5; }
                accA += a5;
                if (b6 != curb) { atomicAdd(&anorm[curb], accA); accA = 0.f; curb = b6; }
                accA += a6;
                if (b7 != curb) { atomicAdd(&anorm[curb], accA); accA = 0.f; curb = b7; }
                accA += a7;
            }
        }
        for (; n < n1; ++n) {
            const f4* xp = (const f4*)(x + (size_t)n * F) + lane;
            f4 r0 = __builtin_nontemporal_load(xp);
            float d0 = r0.x * u4.x + r0.y * u4.y + r0.z * u4.z + r0.w * u4.w;
            #pragma unroll
            for (int off = 32; off; off >>= 1) d0 += __shfl_xor(d0, off);
            int b0 = seg[n];
            float a0 = softplus_f(fabsf(E[b0]) * (d0 + c0) * 0.0625f);
            if (lane == 0) {
                a_arr[n] = a0;
                if (b0 != curb) { atomicAdd(&anorm[curb], accA); accA = 0.f; curb = b0; }
                accA += a0;
            }
        }
        if (lane == 0) atomicAdd(&anorm[curb], accA);
    } else {
        // ----- table build -----
        const int tb = blockIdx.x;
        const int i  = threadIdx.x;
        const float delta = SMAX / (float)(TBL - 1);
        const float wv = Wv[i];

        #pragma unroll
        for (int r = 0; r < 16; ++r) {
            float s  = (float)(tb * 16 + r) * delta;
            float zv = s * wv;
            zbuf[r][i] = zv / (1.f + __expf(-zv));
        }
        __syncthreads();

        float acc[16];
        float bb = b1[i];
        #pragma unroll
        for (int r = 0; r < 16; ++r) acc[r] = bb;
        const f4* w1row = (const f4*)(W1 + (size_t)i * F);
        for (int fc = 0; fc < F / 4; ++fc) {
            f4 w4 = w1row[fc];
            #pragma unroll
            for (int r = 0; r < 16; ++r) {
                f4 z4 = *(const f4*)&zbuf[r][fc * 4];
                acc[r] += w4.x * z4.x + w4.y * z4.y + w4.z * z4.z + w4.w * z4.w;
            }
        }
        __syncthreads();
        #pragma unroll
        for (int r = 0; r < 16; ++r)
            zbuf[r][i] = acc[r] / (1.f + __expf(-acc[r]));
        __syncthreads();

        bb = b2[i];
        #pragma unroll
        for (int r = 0; r < 16; ++r) acc[r] = bb;
        const f4* w2row = (const f4*)(W2 + (size_t)i * F);
        for (int fc = 0; fc < F / 4; ++fc) {
            f4 w4 = w2row[fc];
            #pragma unroll
            for (int r = 0; r < 16; ++r) {
                f4 z4 = *(const f4*)&zbuf[r][fc * 4];
                acc[r] += w4.x * z4.x + w4.y * z4.y + w4.z * z4.z + w4.w * z4.w;
            }
        }
        #pragma unroll
        for (int r = 0; r < 16; ++r) {
            float s = (float)(tb * 16 + r) * delta;
            table[(size_t)(tb * 16 + r) * F + i] = s * wv + acc[r];
        }
    }
}

// ---------------------------------------------------------------------------
// k_out: one 64-row group per wave; lane-parallel index precompute; 8-wide
// gather/store unroll; REGULAR stores (L2 write-combining path).
// ---------------------------------------------------------------------------
__global__ __launch_bounds__(256)
void k_out(const float* __restrict__ a_arr, const int* __restrict__ seg,
           const float* __restrict__ E, const float* __restrict__ anorm,
           const float* __restrict__ table, float* __restrict__ out, int N)
{
    const int lane = threadIdx.x & 63;
    const int wid  = threadIdx.x >> 6;
    const int g0   = blockIdx.x * 4 + wid;
    const int nwaves = gridDim.x * 4;
    const int ngroups = (N + 63) >> 6;
    const float inv_delta = (float)(TBL - 1) / SMAX;

    for (int g = g0; g < ngroups; g += nwaves) {
        const int m0 = g << 6;
        const int cnt = min(64, N - m0);

        int idx = 0;
        if (lane < cnt) {
            int r = m0 + lane;
            int b = seg[r];
            float a = a_arr[r];
            float s = a / (anorm[b] + EPS) * fabsf(E[b]);
            int i0 = (int)(s * inv_delta + 0.5f);
            idx = min(max(i0, 0), TBL - 1) * F;
        }

        if (cnt == 64) {
            #pragma unroll
            for (int r = 0; r < 64; r += 8) {
                int i0 = __builtin_amdgcn_readlane(idx, r);
                int i1 = __builtin_amdgcn_readlane(idx, r + 1);
                int i2 = __builtin_amdgcn_readlane(idx, r + 2);
                int i3 = __builtin_amdgcn_readlane(idx, r + 3);
                int i4 = __builtin_amdgcn_readlane(idx, r + 4);
                int i5 = __builtin_amdgcn_readlane(idx, r + 5);
                int i6 = __builtin_amdgcn_readlane(idx, r + 6);
                int i7 = __builtin_amdgcn_readlane(idx, r + 7);
                f4 t0 = *((const f4*)(table + i0) + lane);
                f4 t1 = *((const f4*)(table + i1) + lane);
                f4 t2 = *((const f4*)(table + i2) + lane);
                f4 t3 = *((const f4*)(table + i3) + lane);
                f4 t4 = *((const f4*)(table + i4) + lane);
                f4 t5 = *((const f4*)(table + i5) + lane);
                f4 t6 = *((const f4*)(table + i6) + lane);
                f4 t7 = *((const f4*)(table + i7) + lane);
                *((f4*)(out + (size_t)(m0 + r)     * F) + lane) = t0;
                *((f4*)(out + (size_t)(m0 + r + 1) * F) + lane) = t1;
                *((f4*)(out + (size_t)(m0 + r + 2) * F) + lane) = t2;
                *((f4*)(out + (size_t)(m0 + r + 3) * F) + lane) = t3;
                *((f4*)(out + (size_t)(m0 + r + 4) * F) + lane) = t4;
                *((f4*)(out + (size_t)(m0 + r + 5) * F) + lane) = t5;
                *((f4*)(out + (size_t)(m0 + r + 6) * F) + lane) = t6;
                *((f4*)(out + (size_t)(m0 + r + 7) * F) + lane) = t7;
            }
        } else {
            for (int r = 0; r < cnt; ++r) {
                int i0 = __shfl(idx, r);
                f4 t0 = *((const f4*)(table + i0) + lane);
                *((f4*)(out + (size_t)(m0 + r) * F) + lane) = t0;
            }
        }
    }
}

// ---------------------------------------------------------------------------
extern "C" void kernel_launch(void* const* d_in, const int* in_sizes, int n_in,
                              void* d_out, int out_size, void* d_ws, size_t ws_size,
                              hipStream_t stream)
{
    const float* x   = (const float*)d_in[0];
    const float* E   = (const float*)d_in[1];
    const int*   seg = (const int*)  d_in[2];
    const float* Wq  = (const float*)d_in[4];
    const float* bq  = (const float*)d_in[5];
    const float* Wk  = (const float*)d_in[6];
    const float* Wv  = (const float*)d_in[7];
    const float* W1  = (const float*)d_in[8];
    const float* b1  = (const float*)d_in[9];
    const float* W2  = (const float*)d_in[10];
    const float* b2  = (const float*)d_in[11];

    const int N = in_sizes[0] / F;
    const int B = in_sizes[1];
    float* out = (float*)d_out;

    float* ws    = (float*)d_ws;
    float* table = ws;                          // TBL*F floats (2 MB)
    float* u     = table + (size_t)TBL * F;     // F
    float* c0    = u + F;                       // 1 (padded to 4)
    float* anorm = c0 + 4;                      // B
    float* a_arr = anorm + B;                   // N

    k_prep<<<F + 1, 256, 0, stream>>>(Wq, bq, Wk, u, c0, anorm, B);

    k_main<<<TBLK + GA, 256, 0, stream>>>(x, E, seg, u, c0, Wv, W1, b1, W2,
                                          b2, a_arr, anorm, table, N);

    k_out<<<1172, 256, 0, stream>>>(a_arr, seg, E, anorm, table, out, N);
}